// Round 1
// baseline (454.318 us; speedup 1.0000x reference)
//
// SelfAttentionWide (B=4, T=1024, E=512, H=8 wide heads) — MI355X gfx950
// Round 4: QKV projection rewritten as 256x256 8-wave counted-vmcnt pipelined GEMM
// (T3+T4+T5 from the technique catalog; ks-major LDS => bank-optimal ds_read_b128
// with linear global_load_lds staging). Scores/softmax/PV/unify unchanged.
// fp32 in/out, bf16 MFMA core.
#include <hip/hip_runtime.h>
#include <stdint.h>

typedef unsigned short u16;
typedef unsigned int u32;
typedef __bf16 bf16_t;
typedef __attribute__((ext_vector_type(8))) bf16_t bf16x8;
typedef __attribute__((ext_vector_type(4))) float floatx4;

__device__ __forceinline__ u16 f2b(float f) {
  u32 u = __float_as_uint(f);
  return (u16)((u + 0x7fffu + ((u >> 16) & 1u)) >> 16);
}

// async 16B/lane global->LDS; LDS dest is wave-uniform base + lane*16
__device__ __forceinline__ void gload_lds16(const u16* g, u16* l) {
  __builtin_amdgcn_global_load_lds(
      (const __attribute__((address_space(1))) u32*)g,
      (__attribute__((address_space(3))) u32*)l, 16, 0, 0);
}

// fused fp32 -> bf16: blockIdx.y selects tensor (all 2M elements)
__global__ __launch_bounds__(256) void cvt_kernel(
    const float* __restrict__ s0, const float* __restrict__ s1,
    const float* __restrict__ s2, const float* __restrict__ s3,
    const float* __restrict__ s4, u16* __restrict__ dbase) {
  const int which = blockIdx.y;
  const float* s = which == 0 ? s0 : which == 1 ? s1 : which == 2 ? s2
                 : which == 3 ? s3 : s4;
  u16* d = dbase + (long)which * 2097152;
  const int i = blockIdx.x * 256 + threadIdx.x;
  const float4 v = ((const float4*)s)[i];
  ushort4 o;
  o.x = f2b(v.x); o.y = f2b(v.y); o.z = f2b(v.z); o.w = f2b(v.w);
  ((ushort4*)d)[i] = o;
}

// out[4096 x 512] fp32 <- broadcast bias rows (pre-pass for split-K atomic unify)
__global__ __launch_bounds__(256) void init_out_kernel(float* __restrict__ out,
                                                       const float* __restrict__ bias) {
  const int i = blockIdx.x * 256 + threadIdx.x;  // 524288 float4s
  const int c4 = i & 127;
  ((float4*)out)[i] = ((const float4*)bias)[c4];
}

enum { A_PLAIN = 0, A_HEADBLK = 1 };   // HEADBLK: A is O in (b,h,t,e), logical (r=(b,t), k=(h,e))
enum { B_PLAIN = 0, B_TRANS = 1 };     // TRANS: B global is (k,n) row-major (V), stage transposed
enum { C_BF16_PLAIN = 0, C_BF16_BHTE = 1, C_F32_PLAIN = 2, C_F32_ATOMIC = 3 };

// ============================================================================
// 256x256 pipelined GEMM: C = A[M x K] @ B[N x K]^T, bf16 in, bf16 BHTE out.
// 512 thr = 8 waves (2M x 4N); per-wave 128x64 output = acc[8][4] 16x16 frags.
// LDS 128KB: 2 dbuf x { A[2ks][256][32] + B[2ks][256][32] } (ks-major, 64B rows
//  => ds_read_b128 is 8 lanes / 4-bank group = conflict-free; staging is linear
//  so global_load_lds applies with NO source swizzle).
// Schedule: 4 phases / K-tile (BK=64): {ds_read frags | stage 2 calls -> buf^1 |
//  s_barrier | lgkmcnt(0) | setprio(1) 16xMFMA setprio(0) | [vmcnt(4)] | s_barrier}.
// vmcnt(4) at phases 1,3 only (never 0 in main loop): steady state keeps exactly
//  4 loads (ks-half of next tile) in flight. Race-free: stage into buf^1 is issued
//  after the barrier that closes all reads of that buffer (prev iteration p3).
// ============================================================================
#define MFMA16(MB)                                                                                 \
  do {                                                                                             \
    acc[(MB) + 0][0] = __builtin_amdgcn_mfma_f32_16x16x32_bf16(A0, B0, acc[(MB) + 0][0], 0, 0, 0); \
    acc[(MB) + 0][1] = __builtin_amdgcn_mfma_f32_16x16x32_bf16(A0, B1, acc[(MB) + 0][1], 0, 0, 0); \
    acc[(MB) + 0][2] = __builtin_amdgcn_mfma_f32_16x16x32_bf16(A0, B2, acc[(MB) + 0][2], 0, 0, 0); \
    acc[(MB) + 0][3] = __builtin_amdgcn_mfma_f32_16x16x32_bf16(A0, B3, acc[(MB) + 0][3], 0, 0, 0); \
    acc[(MB) + 1][0] = __builtin_amdgcn_mfma_f32_16x16x32_bf16(A1, B0, acc[(MB) + 1][0], 0, 0, 0); \
    acc[(MB) + 1][1] = __builtin_amdgcn_mfma_f32_16x16x32_bf16(A1, B1, acc[(MB) + 1][1], 0, 0, 0); \
    acc[(MB) + 1][2] = __builtin_amdgcn_mfma_f32_16x16x32_bf16(A1, B2, acc[(MB) + 1][2], 0, 0, 0); \
    acc[(MB) + 1][3] = __builtin_amdgcn_mfma_f32_16x16x32_bf16(A1, B3, acc[(MB) + 1][3], 0, 0, 0); \
    acc[(MB) + 2][0] = __builtin_amdgcn_mfma_f32_16x16x32_bf16(A2, B0, acc[(MB) + 2][0], 0, 0, 0); \
    acc[(MB) + 2][1] = __builtin_amdgcn_mfma_f32_16x16x32_bf16(A2, B1, acc[(MB) + 2][1], 0, 0, 0); \
    acc[(MB) + 2][2] = __builtin_amdgcn_mfma_f32_16x16x32_bf16(A2, B2, acc[(MB) + 2][2], 0, 0, 0); \
    acc[(MB) + 2][3] = __builtin_amdgcn_mfma_f32_16x16x32_bf16(A2, B3, acc[(MB) + 2][3], 0, 0, 0); \
    acc[(MB) + 3][0] = __builtin_amdgcn_mfma_f32_16x16x32_bf16(A3, B0, acc[(MB) + 3][0], 0, 0, 0); \
    acc[(MB) + 3][1] = __builtin_amdgcn_mfma_f32_16x16x32_bf16(A3, B1, acc[(MB) + 3][1], 0, 0, 0); \
    acc[(MB) + 3][2] = __builtin_amdgcn_mfma_f32_16x16x32_bf16(A3, B2, acc[(MB) + 3][2], 0, 0, 0); \
    acc[(MB) + 3][3] = __builtin_amdgcn_mfma_f32_16x16x32_bf16(A3, B3, acc[(MB) + 3][3], 0, 0, 0); \
  } while (0)

// stage one 8KB call (128 rows x 32 cols) of A or B ks-slab into buf nb
#define STG_A(nb, kt, ks, c)                                             \
  gload_lds16(ag + (long)((c) << 7) * lda + ((kt) << 6) + ((ks) << 5),   \
              &lds[((nb) << 15) + ((ks) << 13) + ((c) << 12) + ls])
#define STG_B(nb, kt, ks, c)                                             \
  gload_lds16(bg + (long)((c) << 7) * ldb + ((kt) << 6) + ((ks) << 5),   \
              &lds[((nb) << 15) + 16384 + ((ks) << 13) + ((c) << 12) + ls])

#define PHASE_SYNC_PRE()                                \
  __builtin_amdgcn_s_barrier();                         \
  asm volatile("s_waitcnt lgkmcnt(0)" ::: "memory");    \
  __builtin_amdgcn_sched_barrier(0);                    \
  __builtin_amdgcn_s_setprio(1)

#define PHASE_SYNC_POST()                               \
  __builtin_amdgcn_s_setprio(0);                        \
  __builtin_amdgcn_s_barrier();                         \
  __builtin_amdgcn_sched_barrier(0)

__global__ __launch_bounds__(512, 2) void gemm256_kernel(
    const u16* __restrict__ A, int lda, long a_zstride,
    const u16* __restrict__ B, int ldb, long b_zstride,
    u16* __restrict__ C, long c_zstride, int K) {
  __shared__ u16 lds[65536];  // 128 KB (gfx950: 160 KB addressable)

  const int tid = threadIdx.x;
  const int wid = tid >> 6, lane = tid & 63;
  const int lrow = lane & 15, quad = lane >> 4;
  const int wm = wid >> 2, wn = wid & 3;

  // XCD-bijective swizzle (nwg=256 per z, 256 % 8 == 0)
  int u = blockIdx.y * 16 + blockIdx.x;
  u = (u & 7) * 32 + (u >> 3);
  const int m0 = (u >> 4) << 8, n0 = (u & 15) << 8;

  const u16* Ab = A + (long)blockIdx.z * a_zstride;
  const u16* Bb = B + (long)blockIdx.z * b_zstride;

  // staging: each call covers 128 rows x 32 cols; wave wid owns 16 rows;
  // lane: row += lane>>2, col = (lane&3)*8  (16B contiguous per lane)
  const u16* ag = Ab + (long)(m0 + (wid << 4) + (lane >> 2)) * lda + ((lane & 3) << 3);
  const u16* bg = Bb + (long)(n0 + (wid << 4) + (lane >> 2)) * ldb + ((lane & 3) << 3);
  const int ls = wid << 9;  // wave chunk (elements) within a 4096-elem call chunk

  // fragment read bases (elements): row-major [256][32] per ks-slab
  const int ard = (((wm << 7) + lrow) << 5) + (quad << 3);
  const int brd = 16384 + (((wn << 6) + lrow) << 5) + (quad << 3);

  floatx4 acc[8][4];
#pragma unroll
  for (int i = 0; i < 8; ++i)
#pragma unroll
    for (int j = 0; j < 4; ++j) acc[i][j] = (floatx4)0.0f;

  // ---- prologue: stage tile 0 -> buf0 (8 calls), then wait first 4 (ks0)
  STG_A(0, 0, 0, 0); STG_A(0, 0, 0, 1);
  STG_B(0, 0, 0, 0); STG_B(0, 0, 0, 1);
  STG_A(0, 0, 1, 0); STG_A(0, 0, 1, 1);
  STG_B(0, 0, 1, 0); STG_B(0, 0, 1, 1);
  asm volatile("s_waitcnt vmcnt(4)" ::: "memory");
  __builtin_amdgcn_s_barrier();
  __builtin_amdgcn_sched_barrier(0);

  const int NT = K >> 6;  // BK=64 K-tiles
  for (int kt = 0; kt < NT; ++kt) {
    const int cur = kt & 1, nb = cur ^ 1;
    const bool pf = (kt + 1 < NT);
    const u16* la = &lds[(cur << 15) + ard];
    const u16* lb = &lds[(cur << 15) + brd];
    bf16x8 A0, A1, A2, A3, B0, B1, B2, B3;

    // ---- phase 0: ks0, mi 0-3 x ni 0-3 | stage A(kt+1) ks0
    A0 = *(const bf16x8*)(la + 0 * 512);
    A1 = *(const bf16x8*)(la + 1 * 512);
    A2 = *(const bf16x8*)(la + 2 * 512);
    A3 = *(const bf16x8*)(la + 3 * 512);
    B0 = *(const bf16x8*)(lb + 0 * 512);
    B1 = *(const bf16x8*)(lb + 1 * 512);
    B2 = *(const bf16x8*)(lb + 2 * 512);
    B3 = *(const bf16x8*)(lb + 3 * 512);
    if (pf) { STG_A(nb, kt + 1, 0, 0); STG_A(nb, kt + 1, 0, 1); }
    PHASE_SYNC_PRE();
    MFMA16(0);
    PHASE_SYNC_POST();

    // ---- phase 1: ks0, mi 4-7 (reuse B) | stage B(kt+1) ks0 | vmcnt(4)
    A0 = *(const bf16x8*)(la + 4 * 512);
    A1 = *(const bf16x8*)(la + 5 * 512);
    A2 = *(const bf16x8*)(la + 6 * 512);
    A3 = *(const bf16x8*)(la + 7 * 512);
    if (pf) { STG_B(nb, kt + 1, 0, 0); STG_B(nb, kt + 1, 0, 1); }
    PHASE_SYNC_PRE();
    MFMA16(4);
    __builtin_amdgcn_s_setprio(0);
    if (pf) asm volatile("s_waitcnt vmcnt(4)" ::: "memory");
    else    asm volatile("s_waitcnt vmcnt(0)" ::: "memory");
    __builtin_amdgcn_s_barrier();
    __builtin_amdgcn_sched_barrier(0);

    // ---- phase 2: ks1, mi 0-3 x ni 0-3 | stage A(kt+1) ks1
    A0 = *(const bf16x8*)(la + 8192 + 0 * 512);
    A1 = *(const bf16x8*)(la + 8192 + 1 * 512);
    A2 = *(const bf16x8*)(la + 8192 + 2 * 512);
    A3 = *(const bf16x8*)(la + 8192 + 3 * 512);
    B0 = *(const bf16x8*)(lb + 8192 + 0 * 512);
    B1 = *(const bf16x8*)(lb + 8192 + 1 * 512);
    B2 = *(const bf16x8*)(lb + 8192 + 2 * 512);
    B3 = *(const bf16x8*)(lb + 8192 + 3 * 512);
    if (pf) { STG_A(nb, kt + 1, 1, 0); STG_A(nb, kt + 1, 1, 1); }
    PHASE_SYNC_PRE();
    MFMA16(0);
    PHASE_SYNC_POST();

    // ---- phase 3: ks1, mi 4-7 (reuse B) | stage B(kt+1) ks1 | vmcnt(4)
    A0 = *(const bf16x8*)(la + 8192 + 4 * 512);
    A1 = *(const bf16x8*)(la + 8192 + 5 * 512);
    A2 = *(const bf16x8*)(la + 8192 + 6 * 512);
    A3 = *(const bf16x8*)(la + 8192 + 7 * 512);
    if (pf) { STG_B(nb, kt + 1, 1, 0); STG_B(nb, kt + 1, 1, 1); }
    PHASE_SYNC_PRE();
    MFMA16(4);
    __builtin_amdgcn_s_setprio(0);
    if (pf) asm volatile("s_waitcnt vmcnt(4)" ::: "memory");
    __builtin_amdgcn_s_barrier();
    __builtin_amdgcn_sched_barrier(0);
  }

  // ---- epilogue: BHTE scatter, D row = quad*4+r, col = lrow (m89 layout)
#pragma unroll
  for (int mi = 0; mi < 8; ++mi) {
#pragma unroll
    for (int ni = 0; ni < 4; ++ni) {
      const int cg = n0 + (wn << 6) + (ni << 4) + lrow;
      const long cbase = (long)blockIdx.z * c_zstride + (long)(cg >> 9) * 524288 + (cg & 511);
#pragma unroll
      for (int r = 0; r < 4; ++r) {
        const int rg = m0 + (wm << 7) + (mi << 4) + (quad << 2) + r;
        C[cbase + (long)(rg >> 10) * 4194304 + (long)(rg & 1023) * 512] = f2b(acc[mi][ni][r]);
      }
    }
  }
}

// C[M x N] = A[M x K] @ B[N x K]^T  (bf16 in, fp32 acc), tile 128x128x32,
// 256 thr = 4 waves (2x2), wave = 4x4 of 16x16x32 MFMA.
// SPLITK: blockIdx.z selects a K-chunk of size K (param = chunk), epilogue atomics.
template <int AMODE, int BMODE, int CMODE, bool CAUSAL_SKIP, bool PV_KLIM, bool HAS_BIAS,
          bool SPLITK>
__global__ __launch_bounds__(256, 2) void gemm_kernel(
    const u16* __restrict__ A, int lda, long a_zstride,
    const u16* __restrict__ B, int ldb, long b_zstride,
    void* __restrict__ C, int ldc, long c_zstride,
    const float* __restrict__ bias, int K, float scale) {
  const int bn = blockIdx.x, bm = blockIdx.y, bz = blockIdx.z;
  if (CAUSAL_SKIP && bn > bm) return;

  int kTiles = K >> 5;
  if (PV_KLIM) kTiles = (bm + 1) * 4;  // rows q in [bm*128,+128) only need k < (bm+1)*128
  const int kbase = SPLITK ? bz * K : 0;

  const u16* Ab = A + (SPLITK ? 0 : (long)bz * a_zstride);
  const u16* Bb = B + (SPLITK ? 0 : (long)bz * b_zstride);

  constexpr int BSTR = (BMODE == B_TRANS) ? 40 : 32;  // pad to 40 (80B, 16B-mult) vs conflicts
  __shared__ u16 sA[128 * 32];
  __shared__ u16 sB[128 * BSTR];

  const int tid = threadIdx.x;
  const int wid = tid >> 6;
  const int lane = tid & 63;
  const int lrow = lane & 15;
  const int quad = lane >> 4;
  const int wm = wid >> 1, wn = wid & 1;
  const int m0 = bm * 128, n0 = bn * 128;

  const int sgr = lane >> 2;        // staging row within 16-row chunk
  const int sgc = (lane & 3) << 3;  // staging col (8 bf16 = 16B)

  floatx4 acc[4][4];
#pragma unroll
  for (int i = 0; i < 4; ++i)
#pragma unroll
    for (int j = 0; j < 4; ++j) acc[i][j] = (floatx4)0.0f;

  for (int kt = 0; kt < kTiles; ++kt) {
    const int k0 = kbase + (kt << 5);
    // ---- stage A tile (async, 16B/lane): wave wid covers rows [wid*32, wid*32+32)
#pragma unroll
    for (int j = 0; j < 2; ++j) {
      const int r = wid * 32 + j * 16 + sgr;
      const u16* g;
      if constexpr (AMODE == A_PLAIN) {
        g = Ab + (long)(m0 + r) * lda + (k0 + sgc);
      } else {
        const int rg = m0 + r, kg = k0 + sgc;
        g = Ab + (long)((rg >> 10) * 8 + (kg >> 9)) * 524288 +
            (long)(rg & 1023) * 512 + (kg & 511);
      }
      gload_lds16(g, &sA[(wid * 32 + j * 16) * 32]);
    }
    // ---- stage B tile
    if constexpr (BMODE == B_PLAIN) {
#pragma unroll
      for (int j = 0; j < 2; ++j) {
        const int r = wid * 32 + j * 16 + sgr;
        const u16* g = Bb + (long)(n0 + r) * ldb + (k0 + sgc);
        gload_lds16(g, &sB[(wid * 32 + j * 16) * 32]);
      }
    } else {
      // transpose-stage V chunk: global (k0+tr, n0+te..te+15) -> sB[n][k]
      const int tr = tid & 31, te = (tid >> 5) << 4;
      const u16* g = Bb + (long)(k0 + tr) * ldb + (n0 + te);
      union { uint4 v[2]; u16 s[16]; } tmp;
      tmp.v[0] = *(const uint4*)g;
      tmp.v[1] = *(const uint4*)(g + 8);
#pragma unroll
      for (int i = 0; i < 16; ++i) sB[(te + i) * BSTR + tr] = tmp.s[i];
    }
    __syncthreads();

    bf16x8 af[4], bfr[4];
#pragma unroll
    for (int i = 0; i < 4; ++i)
      af[i] = *(const bf16x8*)&sA[(wm * 64 + i * 16 + lrow) * 32 + (quad << 3)];
#pragma unroll
    for (int i = 0; i < 4; ++i)
      bfr[i] = *(const bf16x8*)&sB[(wn * 64 + i * 16 + lrow) * BSTR + (quad << 3)];
#pragma unroll
    for (int mi = 0; mi < 4; ++mi)
#pragma unroll
      for (int ni = 0; ni < 4; ++ni)
        acc[mi][ni] = __builtin_amdgcn_mfma_f32_16x16x32_bf16(af[mi], bfr[ni], acc[mi][ni], 0, 0, 0);
    __syncthreads();
  }

  // ---- epilogue: D[row=(quad*4+r)][col=lrow] per 16x16 tile (m89-verified layout)
#pragma unroll
  for (int mi = 0; mi < 4; ++mi) {
#pragma unroll
    for (int ni = 0; ni < 4; ++ni) {
      const int cg = n0 + wn * 64 + ni * 16 + lrow;
      float bv = 0.0f;
      if constexpr (HAS_BIAS) bv = bias[cg];
#pragma unroll
      for (int r = 0; r < 4; ++r) {
        const int rg = m0 + wm * 64 + mi * 16 + quad * 4 + r;
        const float val = acc[mi][ni][r] * scale + bv;
        if constexpr (CMODE == C_F32_PLAIN) {
          ((float*)C)[(long)bz * c_zstride + (long)rg * ldc + cg] = val;
        } else if constexpr (CMODE == C_F32_ATOMIC) {
          atomicAdd(&((float*)C)[(long)rg * ldc + cg], val);
        } else if constexpr (CMODE == C_BF16_PLAIN) {
          ((u16*)C)[(long)bz * c_zstride + (long)rg * ldc + cg] = f2b(val);
        } else {  // C_BF16_BHTE: (r=(b,t), c=(h,e)) -> (b,h,t,e), + z offset
          const long idx = (long)bz * c_zstride +
                           (long)((rg >> 10) * 8 + (cg >> 9)) * 524288 +
                           (long)(rg & 1023) * 512 + (cg & 511);
          ((u16*)C)[idx] = f2b(val);
        }
      }
    }
  }
}

// causal row softmax over S fp32 row q (cols 0..q), write P bf16 in place (lda=2048),
// zero-fill P cols q+1 .. round_up_128(q+1) so the PV GEMM can read full k-tiles.
__global__ __launch_bounds__(256) void softmax_kernel(float* __restrict__ S) {
  const int q = blockIdx.x;
  const long zoff = (long)blockIdx.y * 1048576;
  const float* Srow = S + zoff + (long)q * 1024;
  u16* Prow = (u16*)(S + zoff) + (long)q * 2048;
  const int tid = threadIdx.x;
  const int ncol = q + 1;

  float v[4];
  float m = -3.4e38f;
#pragma unroll
  for (int i = 0; i < 4; ++i) {
    const int c = tid + (i << 8);
    v[i] = (c < ncol) ? Srow[c] : -3.4e38f;
    m = fmaxf(m, v[i]);
  }
#pragma unroll
  for (int off = 32; off > 0; off >>= 1) m = fmaxf(m, __shfl_xor(m, off));
  __shared__ float red[8];
  const int w = tid >> 6;
  if ((tid & 63) == 0) red[w] = m;
  __syncthreads();
  m = fmaxf(fmaxf(red[0], red[1]), fmaxf(red[2], red[3]));

  float s = 0.0f, e[4];
#pragma unroll
  for (int i = 0; i < 4; ++i) {
    const int c = tid + (i << 8);
    e[i] = (c < ncol) ? __expf(v[i] - m) : 0.0f;
    s += e[i];
  }
#pragma unroll
  for (int off = 32; off > 0; off >>= 1) s += __shfl_xor(s, off);
  if ((tid & 63) == 0) red[4 + w] = s;
  __syncthreads();
  s = red[4] + red[5] + red[6] + red[7];
  const float inv = 1.0f / s;
  const int nzend = ((q >> 7) + 1) << 7;
#pragma unroll
  for (int i = 0; i < 4; ++i) {
    const int c = tid + (i << 8);
    if (c < ncol) Prow[c] = f2b(e[i] * inv);
    else if (c < nzend) Prow[c] = 0;
  }
}

extern "C" void kernel_launch(void* const* d_in, const int* in_sizes, int n_in,
                              void* d_out, int out_size, void* d_ws, size_t ws_size,
                              hipStream_t stream) {
  const float* x   = (const float*)d_in[0];
  const float* w_k = (const float*)d_in[1];
  const float* w_q = (const float*)d_in[2];
  const float* w_v = (const float*)d_in[3];
  const float* w_u = (const float*)d_in[4];
  const float* b_u = (const float*)d_in[5];
  float* out = (float*)d_out;
  char* ws = (char*)d_ws;

  const long MB = 1048576;
  // ws layout (bytes): xb 0, wqb 4, wkb 8, wvb 12, wub 16 (bf16, contiguous q/k/v for z-fused
  // QKV gemm); Q 20..52, K 52..84, V 84..116, O 116..148, S fp32 @148
  u16* xb  = (u16*)(ws);
  u16* wqb = (u16*)(ws + 4 * MB);
  u16* wub = (u16*)(ws + 16 * MB);
  u16* Q   = (u16*)(ws + 20 * MB);
  u16* Kb  = (u16*)(ws + 52 * MB);
  u16* V   = (u16*)(ws + 84 * MB);
  u16* O   = (u16*)(ws + 116 * MB);
  float* S = (float*)(ws + 148 * MB);

  // attention group size (bh per pass), by available scratch for S (G*4MB at +148MB)
  int G;
  if (ws_size >= (size_t)(282 * MB)) G = 32;      // full
  else if (ws_size >= (size_t)(180 * MB)) G = 8;  // per-batch
  else G = 1;                                     // per-(b,h)

  const dim3 blk(256);
  const float s2 = 0.044194173824159216f;  // 512^{-1/2} == (e^{-1/4})^2 folded into scores

  // fused fp32 -> bf16 conversions: dest order matches ws layout (x,q,k,v,u)
  cvt_kernel<<<dim3(2048, 5), blk, 0, stream>>>(x, w_q, w_k, w_v, w_u, xb);

  // fused QKV projections, z in {q,k,v}: (4096x512) @ (4096x512)^T -> (b,h,t,e)
  // 256x256 pipelined kernel: grid 16x16x3 = 768 blocks of 512 thr, 128KB LDS (1 blk/CU)
  gemm256_kernel<<<dim3(16, 16, 3), dim3(512), 0, stream>>>(
      xb, 512, 0, wqb, 512, 2097152, Q, 16777216, 512);

  for (int g = 0; g < 32 / G; ++g) {
    const long off = (long)g * G * 524288;
    // scores: S = s2 * Q_bh @ K_bh^T, lower-triangular blocks only
    gemm_kernel<A_PLAIN, B_PLAIN, C_F32_PLAIN, true, false, false, false>
        <<<dim3(8, 8, G), blk, 0, stream>>>(Q + off, 512, 524288, Kb + off, 512, 524288,
                                            S, 1024, 1048576, nullptr, 512, s2);
    softmax_kernel<<<dim3(1024, G), blk, 0, stream>>>(S);
    // O_bh = P @ V_bh  (P bf16 in-place over S, lda=2048; V transpose-staged)
    gemm_kernel<A_PLAIN, B_TRANS, C_BF16_PLAIN, false, true, false, false>
        <<<dim3(4, 8, G), blk, 0, stream>>>((const u16*)S, 2048, 2097152, V + off, 512, 524288,
                                            O + off, 512, 524288, nullptr, 1024, 1.0f);
  }

  // unify: out(fp32) = O2d @ w_u^T + b_u, split-K x4 (K-chunk 1024) for occupancy:
  // grid 4x32x4 = 512 blocks (was 128 @ 5.4% occupancy). Bias via init, partials via atomicAdd.
  init_out_kernel<<<2048, blk, 0, stream>>>(out, b_u);
  gemm_kernel<A_HEADBLK, B_PLAIN, C_F32_ATOMIC, false, false, false, true>
      <<<dim3(4, 32, 4), blk, 0, stream>>>(O, 0, 0, wub, 4096, 0, out, 512, 0,
                                           nullptr, 1024, 1.0f);
}

// Round 2
// 449.476 us; speedup vs baseline: 1.0108x; 1.0108x over previous
//
// SelfAttentionWide (B=4, T=1024, E=512, H=8 wide heads) — MI355X gfx950
// Round 5: gemm256 fixed per post-mortem: (a) T2 swizzle adapted to [*][32] rows
// (read slot ^= (lrow>>1)&3; staging pre-swizzles per-lane GLOBAL col, LDS dest
// stays linear for global_load_lds — G21), (b) 3-half-slab-deep prefetch
// (slab k+3 issued while computing slab k; steady-state vmcnt(8), tail 8->4->0)
// so the load window ~4 phases covers HBM latency at 1 block/CU.
// Scores/softmax/PV/unify unchanged. fp32 in/out, bf16 MFMA core.
#include <hip/hip_runtime.h>
#include <stdint.h>

typedef unsigned short u16;
typedef unsigned int u32;
typedef __bf16 bf16_t;
typedef __attribute__((ext_vector_type(8))) bf16_t bf16x8;
typedef __attribute__((ext_vector_type(4))) float floatx4;

__device__ __forceinline__ u16 f2b(float f) {
  u32 u = __float_as_uint(f);
  return (u16)((u + 0x7fffu + ((u >> 16) & 1u)) >> 16);
}

// async 16B/lane global->LDS; LDS dest is wave-uniform base + lane*16
__device__ __forceinline__ void gload_lds16(const u16* g, u16* l) {
  __builtin_amdgcn_global_load_lds(
      (const __attribute__((address_space(1))) u32*)g,
      (__attribute__((address_space(3))) u32*)l, 16, 0, 0);
}

// fused fp32 -> bf16: blockIdx.y selects tensor (all 2M elements)
__global__ __launch_bounds__(256) void cvt_kernel(
    const float* __restrict__ s0, const float* __restrict__ s1,
    const float* __restrict__ s2, const float* __restrict__ s3,
    const float* __restrict__ s4, u16* __restrict__ dbase) {
  const int which = blockIdx.y;
  const float* s = which == 0 ? s0 : which == 1 ? s1 : which == 2 ? s2
                 : which == 3 ? s3 : s4;
  u16* d = dbase + (long)which * 2097152;
  const int i = blockIdx.x * 256 + threadIdx.x;
  const float4 v = ((const float4*)s)[i];
  ushort4 o;
  o.x = f2b(v.x); o.y = f2b(v.y); o.z = f2b(v.z); o.w = f2b(v.w);
  ((ushort4*)d)[i] = o;
}

// out[4096 x 512] fp32 <- broadcast bias rows (pre-pass for split-K atomic unify)
__global__ __launch_bounds__(256) void init_out_kernel(float* __restrict__ out,
                                                       const float* __restrict__ bias) {
  const int i = blockIdx.x * 256 + threadIdx.x;  // 524288 float4s
  const int c4 = i & 127;
  ((float4*)out)[i] = ((const float4*)bias)[c4];
}

enum { A_PLAIN = 0, A_HEADBLK = 1 };   // HEADBLK: A is O in (b,h,t,e), logical (r=(b,t), k=(h,e))
enum { B_PLAIN = 0, B_TRANS = 1 };     // TRANS: B global is (k,n) row-major (V), stage transposed
enum { C_BF16_PLAIN = 0, C_BF16_BHTE = 1, C_F32_PLAIN = 2, C_F32_ATOMIC = 3 };

// ============================================================================
// 256x256 pipelined GEMM: C = A[M x K] @ B[N x K]^T, bf16 in, bf16 BHTE out.
// 512 thr = 8 waves (2M x 4N); per-wave 128x64 output = acc[8][4] 16x16 frags.
// Pipeline unit = 32-col HALF-SLAB (A 256x32 + B 256x32 = 32KB, 4 gload calls).
// 4 LDS slots (2buf x 2ks), slot(k) = ((k>>1)&1, k&1); issue slab k+3 while
// computing slab k => ~4-phase (~1000cy) load window at 1 block/CU.
// vmcnt: steady 8 (12 in flight max, drain to 8 => slab k+1 landed); tail 8,4,0.
// LDS swizzle (T2 for 64B rows): 16B slot s at row r holds logical col-group
// s ^ ((r>>1)&3); staging pre-swizzles the per-lane global col (linear LDS dest).
// ============================================================================
#define MFMA16(MB)                                                                                 \
  do {                                                                                             \
    acc[(MB) + 0][0] = __builtin_amdgcn_mfma_f32_16x16x32_bf16(A0, B0, acc[(MB) + 0][0], 0, 0, 0); \
    acc[(MB) + 0][1] = __builtin_amdgcn_mfma_f32_16x16x32_bf16(A0, B1, acc[(MB) + 0][1], 0, 0, 0); \
    acc[(MB) + 0][2] = __builtin_amdgcn_mfma_f32_16x16x32_bf16(A0, B2, acc[(MB) + 0][2], 0, 0, 0); \
    acc[(MB) + 0][3] = __builtin_amdgcn_mfma_f32_16x16x32_bf16(A0, B3, acc[(MB) + 0][3], 0, 0, 0); \
    acc[(MB) + 1][0] = __builtin_amdgcn_mfma_f32_16x16x32_bf16(A1, B0, acc[(MB) + 1][0], 0, 0, 0); \
    acc[(MB) + 1][1] = __builtin_amdgcn_mfma_f32_16x16x32_bf16(A1, B1, acc[(MB) + 1][1], 0, 0, 0); \
    acc[(MB) + 1][2] = __builtin_amdgcn_mfma_f32_16x16x32_bf16(A1, B2, acc[(MB) + 1][2], 0, 0, 0); \
    acc[(MB) + 1][3] = __builtin_amdgcn_mfma_f32_16x16x32_bf16(A1, B3, acc[(MB) + 1][3], 0, 0, 0); \
    acc[(MB) + 2][0] = __builtin_amdgcn_mfma_f32_16x16x32_bf16(A2, B0, acc[(MB) + 2][0], 0, 0, 0); \
    acc[(MB) + 2][1] = __builtin_amdgcn_mfma_f32_16x16x32_bf16(A2, B1, acc[(MB) + 2][1], 0, 0, 0); \
    acc[(MB) + 2][2] = __builtin_amdgcn_mfma_f32_16x16x32_bf16(A2, B2, acc[(MB) + 2][2], 0, 0, 0); \
    acc[(MB) + 2][3] = __builtin_amdgcn_mfma_f32_16x16x32_bf16(A2, B3, acc[(MB) + 2][3], 0, 0, 0); \
    acc[(MB) + 3][0] = __builtin_amdgcn_mfma_f32_16x16x32_bf16(A3, B0, acc[(MB) + 3][0], 0, 0, 0); \
    acc[(MB) + 3][1] = __builtin_amdgcn_mfma_f32_16x16x32_bf16(A3, B1, acc[(MB) + 3][1], 0, 0, 0); \
    acc[(MB) + 3][2] = __builtin_amdgcn_mfma_f32_16x16x32_bf16(A3, B2, acc[(MB) + 3][2], 0, 0, 0); \
    acc[(MB) + 3][3] = __builtin_amdgcn_mfma_f32_16x16x32_bf16(A3, B3, acc[(MB) + 3][3], 0, 0, 0); \
  } while (0)

// stage one 128-row x 32-col call (c=0/1) of half-slab kk into its LDS slot
#define STG_A(kk, c)                                                                   \
  gload_lds16(ag + (long)((c) << 7) * lda + ((kk) << 5),                               \
              &lds[((((kk) >> 1) & 1) << 15) + (((kk) & 1) << 13) + ((c) << 12) + ls])
#define STG_B(kk, c)                                                                   \
  gload_lds16(bg + (long)((c) << 7) * ldb + ((kk) << 5),                               \
              &lds[((((kk) >> 1) & 1) << 15) + 16384 + (((kk) & 1) << 13) + ((c) << 12) + ls])

#define PHASE_SYNC_PRE()                                \
  __builtin_amdgcn_s_barrier();                         \
  asm volatile("s_waitcnt lgkmcnt(0)" ::: "memory");    \
  __builtin_amdgcn_sched_barrier(0);                    \
  __builtin_amdgcn_s_setprio(1)

#define PHASE_SYNC_POST()                               \
  __builtin_amdgcn_s_setprio(0);                        \
  __builtin_amdgcn_s_barrier();                         \
  __builtin_amdgcn_sched_barrier(0)

// one half-slab: 2 phases {ds_read A0-3+B0-3 | stage A(k+3) | bar | MFMA16(0) | bar}
// {ds_read A4-7 | stage B(k+3) | bar | MFMA16(4) | vmcnt(VM) | bar}
#define HALF_ITER(kk, DO_STAGE, VM)                                   \
  {                                                                   \
    const int slab_ = ((((kk) >> 1) & 1) << 15) + (((kk) & 1) << 13); \
    const u16* la_ = &lds[slab_ + ard];                               \
    const u16* lb_ = &lds[slab_ + brd];                               \
    A0 = *(const bf16x8*)(la_ + 0 * 512);                             \
    A1 = *(const bf16x8*)(la_ + 1 * 512);                             \
    A2 = *(const bf16x8*)(la_ + 2 * 512);                             \
    A3 = *(const bf16x8*)(la_ + 3 * 512);                             \
    B0 = *(const bf16x8*)(lb_ + 0 * 512);                             \
    B1 = *(const bf16x8*)(lb_ + 1 * 512);                             \
    B2 = *(const bf16x8*)(lb_ + 2 * 512);                             \
    B3 = *(const bf16x8*)(lb_ + 3 * 512);                             \
    if (DO_STAGE) { STG_A((kk) + 3, 0); STG_A((kk) + 3, 1); }         \
    PHASE_SYNC_PRE();                                                 \
    MFMA16(0);                                                        \
    PHASE_SYNC_POST();                                                \
    A0 = *(const bf16x8*)(la_ + 4 * 512);                             \
    A1 = *(const bf16x8*)(la_ + 5 * 512);                             \
    A2 = *(const bf16x8*)(la_ + 6 * 512);                             \
    A3 = *(const bf16x8*)(la_ + 7 * 512);                             \
    if (DO_STAGE) { STG_B((kk) + 3, 0); STG_B((kk) + 3, 1); }         \
    PHASE_SYNC_PRE();                                                 \
    MFMA16(4);                                                        \
    __builtin_amdgcn_s_setprio(0);                                    \
    asm volatile("s_waitcnt vmcnt(" #VM ")" ::: "memory");            \
    __builtin_amdgcn_s_barrier();                                     \
    __builtin_amdgcn_sched_barrier(0);                                \
  }

__global__ __launch_bounds__(512, 2) void gemm256_kernel(
    const u16* __restrict__ A, int lda, long a_zstride,
    const u16* __restrict__ B, int ldb, long b_zstride,
    u16* __restrict__ C, long c_zstride, int K) {
  __shared__ u16 lds[65536];  // 128 KB

  const int tid = threadIdx.x;
  const int wid = tid >> 6, lane = tid & 63;
  const int lrow = lane & 15, quad = lane >> 4;
  const int wm = wid >> 2, wn = wid & 3;

  // XCD-bijective swizzle (nwg=256 per z, 256 % 8 == 0)
  int u = blockIdx.y * 16 + blockIdx.x;
  u = (u & 7) * 32 + (u >> 3);
  const int m0 = (u >> 4) << 8, n0 = (u & 15) << 8;

  const u16* Ab = A + (long)blockIdx.z * a_zstride;
  const u16* Bb = B + (long)blockIdx.z * b_zstride;

  // staging: lane -> (row16 = lane>>2, slot = lane&3); LDS dest linear, global
  // source col-group inverse-swizzled: slot ^ ((row16>>1)&3)  [G21 / m173]
  const int scol = (((lane & 3) ^ ((lane >> 3) & 3)) << 3);
  const u16* ag = Ab + (long)(m0 + (wid << 4) + (lane >> 2)) * lda + scol;
  const u16* bg = Bb + (long)(n0 + (wid << 4) + (lane >> 2)) * ldb + scol;
  const int ls = wid << 9;  // elems: wave chunk within a 4096-elem (128-row) call

  // fragment read bases ([256][32] row-major per half-slab), slot swizzled:
  // physical slot = quad ^ ((row>>1)&3); row bits 1-2 == lrow bits 1-2 here.
  const int qsw = ((quad ^ ((lrow >> 1) & 3)) << 3);
  const int ard = (((wm << 7) + lrow) << 5) + qsw;
  const int brd = 16384 + (((wn << 6) + lrow) << 5) + qsw;

  floatx4 acc[8][4];
#pragma unroll
  for (int i = 0; i < 8; ++i)
#pragma unroll
    for (int j = 0; j < 4; ++j) acc[i][j] = (floatx4)0.0f;

  const int NH = K >> 5;  // half-slab count (requires NH >= 4)

  // ---- prologue: stage slabs 0,1,2 (12 calls, oldest = slab 0), wait slab 0
  STG_A(0, 0); STG_A(0, 1); STG_B(0, 0); STG_B(0, 1);
  STG_A(1, 0); STG_A(1, 1); STG_B(1, 0); STG_B(1, 1);
  STG_A(2, 0); STG_A(2, 1); STG_B(2, 0); STG_B(2, 1);
  asm volatile("s_waitcnt vmcnt(8)" ::: "memory");
  __builtin_amdgcn_s_barrier();
  __builtin_amdgcn_sched_barrier(0);

  bf16x8 A0, A1, A2, A3, B0, B1, B2, B3;

  // steady state: k = 0 .. NH-4, stage k+3, drain to 8 (=> slab k+1 landed)
  for (int k = 0; k <= NH - 4; ++k) HALF_ITER(k, true, 8);
  // tail: no more staging; drain 4, then 0
  HALF_ITER(NH - 3, false, 4);
  HALF_ITER(NH - 2, false, 0);
  {  // last half-slab: no stage, no wait, no trailing barrier
    const int slab_ = ((((NH - 1) >> 1) & 1) << 15) + (((NH - 1) & 1) << 13);
    const u16* la_ = &lds[slab_ + ard];
    const u16* lb_ = &lds[slab_ + brd];
    A0 = *(const bf16x8*)(la_ + 0 * 512);
    A1 = *(const bf16x8*)(la_ + 1 * 512);
    A2 = *(const bf16x8*)(la_ + 2 * 512);
    A3 = *(const bf16x8*)(la_ + 3 * 512);
    B0 = *(const bf16x8*)(lb_ + 0 * 512);
    B1 = *(const bf16x8*)(lb_ + 1 * 512);
    B2 = *(const bf16x8*)(lb_ + 2 * 512);
    B3 = *(const bf16x8*)(lb_ + 3 * 512);
    PHASE_SYNC_PRE();
    MFMA16(0);
    PHASE_SYNC_POST();
    A0 = *(const bf16x8*)(la_ + 4 * 512);
    A1 = *(const bf16x8*)(la_ + 5 * 512);
    A2 = *(const bf16x8*)(la_ + 6 * 512);
    A3 = *(const bf16x8*)(la_ + 7 * 512);
    PHASE_SYNC_PRE();
    MFMA16(4);
    __builtin_amdgcn_s_setprio(0);
  }

  // ---- epilogue: BHTE scatter, D row = quad*4+r, col = lrow (m89 layout)
#pragma unroll
  for (int mi = 0; mi < 8; ++mi) {
#pragma unroll
    for (int ni = 0; ni < 4; ++ni) {
      const int cg = n0 + (wn << 6) + (ni << 4) + lrow;
      const long cbase = (long)blockIdx.z * c_zstride + (long)(cg >> 9) * 524288 + (cg & 511);
#pragma unroll
      for (int r = 0; r < 4; ++r) {
        const int rg = m0 + (wm << 7) + (mi << 4) + (quad << 2) + r;
        C[cbase + (long)(rg >> 10) * 4194304 + (long)(rg & 1023) * 512] = f2b(acc[mi][ni][r]);
      }
    }
  }
}

// C[M x N] = A[M x K] @ B[N x K]^T  (bf16 in, fp32 acc), tile 128x128x32,
// 256 thr = 4 waves (2x2), wave = 4x4 of 16x16x32 MFMA.
// SPLITK: blockIdx.z selects a K-chunk of size K (param = chunk), epilogue atomics.
template <int AMODE, int BMODE, int CMODE, bool CAUSAL_SKIP, bool PV_KLIM, bool HAS_BIAS,
          bool SPLITK>
__global__ __launch_bounds__(256, 2) void gemm_kernel(
    const u16* __restrict__ A, int lda, long a_zstride,
    const u16* __restrict__ B, int ldb, long b_zstride,
    void* __restrict__ C, int ldc, long c_zstride,
    const float* __restrict__ bias, int K, float scale) {
  const int bn = blockIdx.x, bm = blockIdx.y, bz = blockIdx.z;
  if (CAUSAL_SKIP && bn > bm) return;

  int kTiles = K >> 5;
  if (PV_KLIM) kTiles = (bm + 1) * 4;  // rows q in [bm*128,+128) only need k < (bm+1)*128
  const int kbase = SPLITK ? bz * K : 0;

  const u16* Ab = A + (SPLITK ? 0 : (long)bz * a_zstride);
  const u16* Bb = B + (SPLITK ? 0 : (long)bz * b_zstride);

  constexpr int BSTR = (BMODE == B_TRANS) ? 40 : 32;  // pad to 40 (80B, 16B-mult) vs conflicts
  __shared__ u16 sA[128 * 32];
  __shared__ u16 sB[128 * BSTR];

  const int tid = threadIdx.x;
  const int wid = tid >> 6;
  const int lane = tid & 63;
  const int lrow = lane & 15;
  const int quad = lane >> 4;
  const int wm = wid >> 1, wn = wid & 1;
  const int m0 = bm * 128, n0 = bn * 128;

  const int sgr = lane >> 2;        // staging row within 16-row chunk
  const int sgc = (lane & 3) << 3;  // staging col (8 bf16 = 16B)

  floatx4 acc[4][4];
#pragma unroll
  for (int i = 0; i < 4; ++i)
#pragma unroll
    for (int j = 0; j < 4; ++j) acc[i][j] = (floatx4)0.0f;

  for (int kt = 0; kt < kTiles; ++kt) {
    const int k0 = kbase + (kt << 5);
    // ---- stage A tile (async, 16B/lane): wave wid covers rows [wid*32, wid*32+32)
#pragma unroll
    for (int j = 0; j < 2; ++j) {
      const int r = wid * 32 + j * 16 + sgr;
      const u16* g;
      if constexpr (AMODE == A_PLAIN) {
        g = Ab + (long)(m0 + r) * lda + (k0 + sgc);
      } else {
        const int rg = m0 + r, kg = k0 + sgc;
        g = Ab + (long)((rg >> 10) * 8 + (kg >> 9)) * 524288 +
            (long)(rg & 1023) * 512 + (kg & 511);
      }
      gload_lds16(g, &sA[(wid * 32 + j * 16) * 32]);
    }
    // ---- stage B tile
    if constexpr (BMODE == B_PLAIN) {
#pragma unroll
      for (int j = 0; j < 2; ++j) {
        const int r = wid * 32 + j * 16 + sgr;
        const u16* g = Bb + (long)(n0 + r) * ldb + (k0 + sgc);
        gload_lds16(g, &sB[(wid * 32 + j * 16) * 32]);
      }
    } else {
      // transpose-stage V chunk: global (k0+tr, n0+te..te+15) -> sB[n][k]
      const int tr = tid & 31, te = (tid >> 5) << 4;
      const u16* g = Bb + (long)(k0 + tr) * ldb + (n0 + te);
      union { uint4 v[2]; u16 s[16]; } tmp;
      tmp.v[0] = *(const uint4*)g;
      tmp.v[1] = *(const uint4*)(g + 8);
#pragma unroll
      for (int i = 0; i < 16; ++i) sB[(te + i) * BSTR + tr] = tmp.s[i];
    }
    __syncthreads();

    bf16x8 af[4], bfr[4];
#pragma unroll
    for (int i = 0; i < 4; ++i)
      af[i] = *(const bf16x8*)&sA[(wm * 64 + i * 16 + lrow) * 32 + (quad << 3)];
#pragma unroll
    for (int i = 0; i < 4; ++i)
      bfr[i] = *(const bf16x8*)&sB[(wn * 64 + i * 16 + lrow) * BSTR + (quad << 3)];
#pragma unroll
    for (int mi = 0; mi < 4; ++mi)
#pragma unroll
      for (int ni = 0; ni < 4; ++ni)
        acc[mi][ni] = __builtin_amdgcn_mfma_f32_16x16x32_bf16(af[mi], bfr[ni], acc[mi][ni], 0, 0, 0);
    __syncthreads();
  }

  // ---- epilogue: D[row=(quad*4+r)][col=lrow] per 16x16 tile (m89-verified layout)
#pragma unroll
  for (int mi = 0; mi < 4; ++mi) {
#pragma unroll
    for (int ni = 0; ni < 4; ++ni) {
      const int cg = n0 + wn * 64 + ni * 16 + lrow;
      float bv = 0.0f;
      if constexpr (HAS_BIAS) bv = bias[cg];
#pragma unroll
      for (int r = 0; r < 4; ++r) {
        const int rg = m0 + wm * 64 + mi * 16 + quad * 4 + r;
        const float val = acc[mi][ni][r] * scale + bv;
        if constexpr (CMODE == C_F32_PLAIN) {
          ((float*)C)[(long)bz * c_zstride + (long)rg * ldc + cg] = val;
        } else if constexpr (CMODE == C_F32_ATOMIC) {
          atomicAdd(&((float*)C)[(long)rg * ldc + cg], val);
        } else if constexpr (CMODE == C_BF16_PLAIN) {
          ((u16*)C)[(long)bz * c_zstride + (long)rg * ldc + cg] = f2b(val);
        } else {  // C_BF16_BHTE: (r=(b,t), c=(h,e)) -> (b,h,t,e), + z offset
          const long idx = (long)bz * c_zstride +
                           (long)((rg >> 10) * 8 + (cg >> 9)) * 524288 +
                           (long)(rg & 1023) * 512 + (cg & 511);
          ((u16*)C)[idx] = f2b(val);
        }
      }
    }
  }
}

// causal row softmax over S fp32 row q (cols 0..q), write P bf16 in place (lda=2048),
// zero-fill P cols q+1 .. round_up_128(q+1) so the PV GEMM can read full k-tiles.
__global__ __launch_bounds__(256) void softmax_kernel(float* __restrict__ S) {
  const int q = blockIdx.x;
  const long zoff = (long)blockIdx.y * 1048576;
  const float* Srow = S + zoff + (long)q * 1024;
  u16* Prow = (u16*)(S + zoff) + (long)q * 2048;
  const int tid = threadIdx.x;
  const int ncol = q + 1;

  float v[4];
  float m = -3.4e38f;
#pragma unroll
  for (int i = 0; i < 4; ++i) {
    const int c = tid + (i << 8);
    v[i] = (c < ncol) ? Srow[c] : -3.4e38f;
    m = fmaxf(m, v[i]);
  }
#pragma unroll
  for (int off = 32; off > 0; off >>= 1) m = fmaxf(m, __shfl_xor(m, off));
  __shared__ float red[8];
  const int w = tid >> 6;
  if ((tid & 63) == 0) red[w] = m;
  __syncthreads();
  m = fmaxf(fmaxf(red[0], red[1]), fmaxf(red[2], red[3]));

  float s = 0.0f, e[4];
#pragma unroll
  for (int i = 0; i < 4; ++i) {
    const int c = tid + (i << 8);
    e[i] = (c < ncol) ? __expf(v[i] - m) : 0.0f;
    s += e[i];
  }
#pragma unroll
  for (int off = 32; off > 0; off >>= 1) s += __shfl_xor(s, off);
  if ((tid & 63) == 0) red[4 + w] = s;
  __syncthreads();
  s = red[4] + red[5] + red[6] + red[7];
  const float inv = 1.0f / s;
  const int nzend = ((q >> 7) + 1) << 7;
#pragma unroll
  for (int i = 0; i < 4; ++i) {
    const int c = tid + (i << 8);
    if (c < ncol) Prow[c] = f2b(e[i] * inv);
    else if (c < nzend) Prow[c] = 0;
  }
}

extern "C" void kernel_launch(void* const* d_in, const int* in_sizes, int n_in,
                              void* d_out, int out_size, void* d_ws, size_t ws_size,
                              hipStream_t stream) {
  const float* x   = (const float*)d_in[0];
  const float* w_k = (const float*)d_in[1];
  const float* w_q = (const float*)d_in[2];
  const float* w_v = (const float*)d_in[3];
  const float* w_u = (const float*)d_in[4];
  const float* b_u = (const float*)d_in[5];
  float* out = (float*)d_out;
  char* ws = (char*)d_ws;

  const long MB = 1048576;
  // ws layout (bytes): xb 0, wqb 4, wkb 8, wvb 12, wub 16 (bf16, contiguous q/k/v for z-fused
  // QKV gemm); Q 20..52, K 52..84, V 84..116, O 116..148, S fp32 @148
  u16* xb  = (u16*)(ws);
  u16* wqb = (u16*)(ws + 4 * MB);
  u16* wub = (u16*)(ws + 16 * MB);
  u16* Q   = (u16*)(ws + 20 * MB);
  u16* Kb  = (u16*)(ws + 52 * MB);
  u16* V   = (u16*)(ws + 84 * MB);
  u16* O   = (u16*)(ws + 116 * MB);
  float* S = (float*)(ws + 148 * MB);

  // attention group size (bh per pass), by available scratch for S (G*4MB at +148MB)
  int G;
  if (ws_size >= (size_t)(282 * MB)) G = 32;      // full
  else if (ws_size >= (size_t)(180 * MB)) G = 8;  // per-batch
  else G = 1;                                     // per-(b,h)

  const dim3 blk(256);
  const float s2 = 0.044194173824159216f;  // 512^{-1/2} == (e^{-1/4})^2 folded into scores

  // fused fp32 -> bf16 conversions: dest order matches ws layout (x,q,k,v,u)
  cvt_kernel<<<dim3(2048, 5), blk, 0, stream>>>(x, w_q, w_k, w_v, w_u, xb);

  // fused QKV projections, z in {q,k,v}: (4096x512) @ (4096x512)^T -> (b,h,t,e)
  // 256x256 pipelined kernel: grid 16x16x3 = 768 blocks of 512 thr, 128KB LDS (1 blk/CU)
  gemm256_kernel<<<dim3(16, 16, 3), dim3(512), 0, stream>>>(
      xb, 512, 0, wqb, 512, 2097152, Q, 16777216, 512);

  for (int g = 0; g < 32 / G; ++g) {
    const long off = (long)g * G * 524288;
    // scores: S = s2 * Q_bh @ K_bh^T, lower-triangular blocks only
    gemm_kernel<A_PLAIN, B_PLAIN, C_F32_PLAIN, true, false, false, false>
        <<<dim3(8, 8, G), blk, 0, stream>>>(Q + off, 512, 524288, Kb + off, 512, 524288,
                                            S, 1024, 1048576, nullptr, 512, s2);
    softmax_kernel<<<dim3(1024, G), blk, 0, stream>>>(S);
    // O_bh = P @ V_bh  (P bf16 in-place over S, lda=2048; V transpose-staged)
    gemm_kernel<A_PLAIN, B_TRANS, C_BF16_PLAIN, false, true, false, false>
        <<<dim3(4, 8, G), blk, 0, stream>>>((const u16*)S, 2048, 2097152, V + off, 512, 524288,
                                            O + off, 512, 524288, nullptr, 1024, 1.0f);
  }

  // unify: out(fp32) = O2d @ w_u^T + b_u, split-K x4 (K-chunk 1024) for occupancy:
  // grid 4x32x4 = 512 blocks (was 128 @ 5.4% occupancy). Bias via init, partials via atomicAdd.
  init_out_kernel<<<2048, blk, 0, stream>>>(out, b_u);
  gemm_kernel<A_HEADBLK, B_PLAIN, C_F32_ATOMIC, false, false, false, true>
      <<<dim3(4, 32, 4), blk, 0, stream>>>(O, 0, 0, wub, 4096, 0, out, 512, 0,
                                           nullptr, 1024, 1.0f);
}